// Round 13
// baseline (226.426 us; speedup 1.0000x reference)
//
#include <hip/hip_runtime.h>
#include <hip/hip_bf16.h>

#define GK 1024

typedef __attribute__((ext_vector_type(8))) short bf16x8;
typedef __attribute__((ext_vector_type(4))) float f32x4;
typedef __attribute__((ext_vector_type(16))) float f32x16;
typedef __attribute__((ext_vector_type(4))) unsigned short ushort4v;

__device__ __forceinline__ f32x4 mfma16(bf16x8 a, bf16x8 b, f32x4 c) {
  return __builtin_amdgcn_mfma_f32_16x16x32_bf16(a, b, c, 0, 0, 0);
}
__device__ __forceinline__ f32x16 mfma32(bf16x8 a, bf16x8 b, f32x16 c) {
  return __builtin_amdgcn_mfma_f32_32x32x16_bf16(a, b, c, 0, 0, 0);
}

__device__ __forceinline__ unsigned short f2b(float f) {
  union { float f; unsigned int u; } x; x.f = f;
  return (unsigned short)((x.u + 0x7fffu + ((x.u >> 16) & 1u)) >> 16);
}

// packed f32x2 -> bf16x2 (RNE); lowers to v_cvt_pk_bf16_f32
__device__ __forceinline__ unsigned int pk2(float lo, float hi) {
  float2 f; f.x = lo; f.y = hi;
  __hip_bfloat162 t = __float22bfloat162_rn(f);
  union { __hip_bfloat162 b; unsigned int u; } c; c.b = t;
  return c.u;
}

__device__ __forceinline__ float fexp2(float x) {
#if __has_builtin(__builtin_amdgcn_exp2f)
  return __builtin_amdgcn_exp2f(x);
#else
  return exp2f(x);
#endif
}
__device__ __forceinline__ float frcp(float x) {
#if __has_builtin(__builtin_amdgcn_rcpf)
  return __builtin_amdgcn_rcpf(x);
#else
  return 1.0f / x;
#endif
}

// async global->LDS, 16B per lane; LDS dest = wave-uniform base + lane*16
__device__ __forceinline__ void gl_lds16(const void* g, void* l) {
  __builtin_amdgcn_global_load_lds(
      (const __attribute__((address_space(1))) unsigned int*)g,
      (__attribute__((address_space(3))) unsigned int*)l, 16, 0, 0);
}

// ---------------- convert fp32 -> bf16 (inp + 4 weight mats) ----------------
__global__ __launch_bounds__(256) void convert_kernel(
    const float* __restrict__ inp,
    const float* __restrict__ wq, const float* __restrict__ wk,
    const float* __restrict__ wv, const float* __restrict__ wo,
    unsigned short* __restrict__ Xb, unsigned short* __restrict__ Wcat)
{
  const size_t XN = (size_t)4194304;  // 2*2048*1024
  size_t i = ((size_t)blockIdx.x * 256 + threadIdx.x) * 4;
  const float* src; unsigned short* dst; size_t off;
  if (i < XN) {
    src = inp; dst = Xb; off = i;
  } else {
    size_t j = i - XN;
    int w = (int)(j >> 20);
    off = j & 1048575u;
    src = (w == 0) ? wq : (w == 1) ? wk : (w == 2) ? wv : wo;
    dst = Wcat + ((size_t)w << 20);
  }
  f32x4 v = *(const f32x4*)(src + off);
  ushort4v o;
#pragma unroll
  for (int t = 0; t < 4; ++t) o[t] = f2b(v[t]);
  *(ushort4v*)(dst + off) = o;
}

// ------------- GEMM mainloop via global_load_lds (m97 pattern) --------------
// R8-proven form: 16KB LDS, two barriers per K-step. (The 1-barrier dbuf
// variant measured ~5-8us slower overall: its end-of-iter barrier drains the
// just-issued prefetch anyway, and 2x LDS cost occupancy.)
__device__ __forceinline__ void gemm_mainloop(
    const unsigned short* __restrict__ A, const unsigned short* __restrict__ Wt,
    int m0, int n0, int tid, unsigned short* As, unsigned short* Bs,
    f32x4 (&acc)[4][4])
{
  const int lane = tid & 63;
  const int wave = tid >> 6;
  const int wr = wave >> 1, wc = wave & 1;
  const int lq = lane & 15, g = lane >> 4;

  const int r_in = lane >> 2;          // 0..15
  const int c8 = (lane & 3) * 8;       // element col: 0,8,16,24

  const unsigned short* Ap0 = A + (size_t)(m0 + wave * 32 + r_in) * GK + c8;
  const unsigned short* Ap1 = Ap0 + (size_t)16 * GK;
  const unsigned short* Wp0 = Wt + (size_t)(n0 + wave * 32 + r_in) * GK + c8;
  const unsigned short* Wp1 = Wp0 + (size_t)16 * GK;
  unsigned short* As0 = As + wave * 1024;   // elements (2KB per wave)
  unsigned short* Bs0 = Bs + wave * 1024;

  for (int kt = 0; kt < GK / 32; ++kt) {
    const int k0 = kt * 32;
    __syncthreads();                       // prev tile's reads done
    gl_lds16(Ap0 + k0, As0);
    gl_lds16(Ap1 + k0, As0 + 512);
    gl_lds16(Wp0 + k0, Bs0);
    gl_lds16(Wp1 + k0, Bs0 + 512);
    __syncthreads();                       // drains vmcnt -> LDS valid
    bf16x8 af[4], bfr[4];
#pragma unroll
    for (int i = 0; i < 4; ++i)
      af[i] = *(const bf16x8*)(As + (wr * 64 + i * 16 + lq) * 32 + g * 8);
#pragma unroll
    for (int j = 0; j < 4; ++j)
      bfr[j] = *(const bf16x8*)(Bs + (wc * 64 + j * 16 + lq) * 32 + g * 8);
#pragma unroll
    for (int i = 0; i < 4; ++i)
#pragma unroll
      for (int j = 0; j < 4; ++j)
        acc[i][j] = mfma16(af[i], bfr[j], acc[i][j]);
  }
}

// ---------------- QKV projection GEMM (z: 0=Q, 1=K, 2=V-transposed) ----------
__global__ __launch_bounds__(256) void gemm_qkv(
    const unsigned short* __restrict__ X, const unsigned short* __restrict__ Wcat,
    unsigned short* __restrict__ Qb, unsigned short* __restrict__ Kb,
    unsigned short* __restrict__ Vt)
{
  __shared__ unsigned short As[4096];
  __shared__ unsigned short Bs[4096];
  f32x4 acc[4][4];
#pragma unroll
  for (int i = 0; i < 4; ++i)
#pragma unroll
    for (int j = 0; j < 4; ++j) acc[i][j] = (f32x4){0.f, 0.f, 0.f, 0.f};

  const int z = blockIdx.z;
  const int m0 = blockIdx.x * 128, n0 = blockIdx.y * 128;
  gemm_mainloop(X, Wcat + ((size_t)z << 20), m0, n0, (int)threadIdx.x, As, Bs, acc);

  const int lane = threadIdx.x & 63;
  const int wave = threadIdx.x >> 6;
  const int wr = wave >> 1, wc = wave & 1, lq = lane & 15, g = lane >> 4;

  if (z < 2) {
    unsigned short* C = z ? Kb : Qb;
#pragma unroll
    for (int i = 0; i < 4; ++i)
#pragma unroll
      for (int j = 0; j < 4; ++j) {
        int col = n0 + wc * 64 + j * 16 + lq;
#pragma unroll
        for (int r = 0; r < 4; ++r) {
          int row = m0 + wr * 64 + i * 16 + g * 4 + r;
          C[(size_t)row * 1024 + col] = f2b(acc[i][j][r]);
        }
      }
  } else {
    // V transposed: Vt[(b*1024 + n)][s], n = h*64+dk
#pragma unroll
    for (int i = 0; i < 4; ++i)
#pragma unroll
      for (int j = 0; j < 4; ++j) {
        int col = n0 + wc * 64 + j * 16 + lq;
        int row0 = m0 + wr * 64 + i * 16 + g * 4;
        int b = row0 >> 11;
        int s = row0 & 2047;
        ushort4v pv;
#pragma unroll
        for (int r = 0; r < 4; ++r) pv[r] = f2b(acc[i][j][r]);
        *(ushort4v*)(Vt + (size_t)(b * 1024 + col) * 2048 + s) = pv;
      }
  }
}

// ---------------- output projection GEMM (fp32 out) ----------------
__global__ __launch_bounds__(256) void gemm_out(
    const unsigned short* __restrict__ Ob, const unsigned short* __restrict__ Wo,
    float* __restrict__ out)
{
  __shared__ unsigned short As[4096];
  __shared__ unsigned short Bs[4096];
  f32x4 acc[4][4];
#pragma unroll
  for (int i = 0; i < 4; ++i)
#pragma unroll
    for (int j = 0; j < 4; ++j) acc[i][j] = (f32x4){0.f, 0.f, 0.f, 0.f};

  const int m0 = blockIdx.x * 128, n0 = blockIdx.y * 128;
  gemm_mainloop(Ob, Wo, m0, n0, (int)threadIdx.x, As, Bs, acc);

  const int lane = threadIdx.x & 63;
  const int wave = threadIdx.x >> 6;
  const int wr = wave >> 1, wc = wave & 1, lq = lane & 15, g = lane >> 4;
#pragma unroll
  for (int i = 0; i < 4; ++i)
#pragma unroll
    for (int j = 0; j < 4; ++j) {
      int col = n0 + wc * 64 + j * 16 + lq;
#pragma unroll
      for (int r = 0; r < 4; ++r) {
        int row = m0 + wr * 64 + i * 16 + g * 4 + r;
        out[(size_t)row * 1024 + col] = acc[i][j][r];
      }
    }
}

// ---------------- attention tile chain: softcap + pack + PV ----------------
// Poly-tanh softcap: p = exp2(C1*tanh(y) - C1), y = (raw/8 + bias)/30.
__device__ __forceinline__ void attn_chain(
    const bf16x8 (&qf)[4], const f32x4 (&bvs)[4],
    bf16x8 kf0, bf16x8 kf1, bf16x8 kf2, bf16x8 kf3,
    bf16x8 va00, bf16x8 va01, bf16x8 va10, bf16x8 va11,
    bool msk, int ql, int hi,
    f32x16& o0, f32x16& o1, float& pls)
{
  const float INV30 = 0.033333333333f;
  const float C3 = -0.333333333f, C5 = 0.133333333f;
  const float C1 = 43.28085122666891f;   // 30*log2(e)

  f32x16 st = {0.f,0.f,0.f,0.f,0.f,0.f,0.f,0.f,0.f,0.f,0.f,0.f,0.f,0.f,0.f,0.f};
  st = mfma32(kf0, qf[0], st);
  st = mfma32(kf1, qf[1], st);
  st = mfma32(kf2, qf[2], st);
  st = mfma32(kf3, qf[3], st);

  float p[16];
#pragma unroll
  for (int reg = 0; reg < 16; ++reg) {
    float v = fmaf(st[reg], 0.125f, bvs[reg >> 2][reg & 3]);
    float y = v * INV30;
    float y2 = y * y;
    float t = y * fmaf(y2, fmaf(y2, C5, C3), 1.0f);
    p[reg] = fexp2(fmaf(t, C1, -C1));
  }
  if (msk) {
#pragma unroll
    for (int reg = 0; reg < 16; ++reg) {
      int krow = (reg & 3) + 8 * (reg >> 2) + 4 * hi;
      p[reg] = (krow <= ql) ? p[reg] : 0.f;
    }
  }
  float a0 = (p[0] + p[1]) + (p[2] + p[3]);
  float a1 = (p[4] + p[5]) + (p[6] + p[7]);
  float a2 = (p[8] + p[9]) + (p[10] + p[11]);
  float a3 = (p[12] + p[13]) + (p[14] + p[15]);
  pls += (a0 + a1) + (a2 + a3);

  unsigned int wv[8];
#pragma unroll
  for (int j = 0; j < 8; ++j) wv[j] = pk2(p[2 * j], p[2 * j + 1]);
  unsigned int x0 = hi ? wv[0] : wv[2], x1 = hi ? wv[1] : wv[3];
  x0 = __shfl_xor(x0, 32); x1 = __shfl_xor(x1, 32);
  unsigned int y0 = hi ? wv[4] : wv[6], y1 = hi ? wv[5] : wv[7];
  y0 = __shfl_xor(y0, 32); y1 = __shfl_xor(y1, 32);
  union { unsigned int u[4]; bf16x8 v; } B0, B1;
  B0.u[0] = hi ? x0 : wv[0]; B0.u[1] = hi ? x1 : wv[1];
  B0.u[2] = hi ? wv[2] : x0; B0.u[3] = hi ? wv[3] : x1;
  B1.u[0] = hi ? y0 : wv[4]; B1.u[1] = hi ? y1 : wv[5];
  B1.u[2] = hi ? wv[6] : y0; B1.u[3] = hi ? wv[7] : y1;

  o0 = mfma32(va00, B0.v, o0);
  o0 = mfma32(va01, B1.v, o0);
  o1 = mfma32(va10, B0.v, o1);
  o1 = mfma32(va11, B1.v, o1);
}

// ---- fused flash attention: symmetric q-pair, split-k x4, per-wave staged ----
// R11 structure (best measured: 69.4us): SINGLE-buffer staging, 8KB/wave,
// 36KB/block, stage(kt) -> vmcnt(0) -> compute(kt), no barriers in loop.
// NEW: launch_bounds(256,3) -> reg budget 168 total. Measured need is 172
// (108 arch + 64 acc): allocator must trim ~4 arch regs -> 3 waves/SIMD
// (12 waves/CU, +50% TLP). Go/no-go: VGPR_Count ~100-104 and WRITE_SIZE ~8MB
// (ballooned WRITE = spill -> revert to (256,2)). NEVER (,4): clamps total
// to 128 -> the 64-reg accumulator spills (R9/R10: 3-5x regression).
__global__ __launch_bounds__(256, 3) void attn_fwd(
    const unsigned short* __restrict__ Qb, const unsigned short* __restrict__ Kb,
    const unsigned short* __restrict__ Vt, const float* __restrict__ bias,
    unsigned short* __restrict__ Ob)
{
  __shared__ __attribute__((aligned(16))) unsigned char lds[36352];

  const int tid = (int)threadIdx.x;
  const int lane = tid & 63;
  const int w = tid >> 6;
  // XCD affinity: xcd = bid&7 owns heads [4*xcd, 4*xcd+4)
  const int bid = (int)blockIdx.x;
  const int bh = (bid & 7) * 4 + ((bid >> 3) & 3);
  const int qp = bid >> 5;                 // 0..31
  const int b = bh >> 4, h = bh & 15;
  const int tA = qp, tB = 63 - qp;
  const int q0A = tA * 32, q0B = tB * 32;
  const int ql = lane & 31;
  const int hi = lane >> 5;

  // ---- Q fragments (one-time gather) ----
  const unsigned short* QpA = Qb + (size_t)(b * 2048 + q0A + ql) * 1024 + h * 64 + 8 * hi;
  const unsigned short* QpB = Qb + (size_t)(b * 2048 + q0B + ql) * 1024 + h * 64 + 8 * hi;
  bf16x8 qfA[4], qfB[4];
#pragma unroll
  for (int c = 0; c < 4; ++c) {
    qfA[c] = *(const bf16x8*)(QpA + 16 * c);
    qfB[c] = *(const bf16x8*)(QpB + 16 * c);
  }

  // ---- per-lane staging sources (inverse-swizzled, rule #21) ----
  const unsigned short* KsrcL = Kb + (size_t)(b * 2048 + (lane >> 3)) * 1024
                                + h * 64 + (((lane & 7) ^ ((lane >> 3) & 7)) << 3);
  const unsigned short* VsrcL = Vt + (size_t)(bh * 64 + (lane >> 2)) * 2048
                                + (((lane & 3) ^ ((lane >> 2) & 3)) << 3);
  unsigned char* const Kdst = lds + w * 8192;   // K 4KB, V 4KB per wave
  unsigned char* const Vdst = Kdst + 4096;

  const float* BpA = bias + (size_t)b * 4194304 + (size_t)(q0A + ql) * 2048 + 4 * hi;
  const float* BpB = bias + (size_t)b * 4194304 + (size_t)(q0B + ql) * 2048 + 4 * hi;

  float plsA = 0.f, plsB = 0.f;
  f32x16 oA0 = {0.f,0.f,0.f,0.f,0.f,0.f,0.f,0.f,0.f,0.f,0.f,0.f,0.f,0.f,0.f,0.f};
  f32x16 oA1 = oA0, oB0 = oA0, oB1 = oA0;

  auto stageKV = [&](int kt) {
#pragma unroll
    for (int j = 0; j < 4; ++j)
      gl_lds16(KsrcL + (size_t)kt * 32768 + j * 8192, Kdst + j * 1024);
#pragma unroll
    for (int j = 0; j < 4; ++j)
      gl_lds16(VsrcL + (size_t)j * 32768 + kt * 32, Vdst + j * 1024);
  };

  for (int kt = w; kt <= tB; kt += 4) {
    __builtin_amdgcn_sched_barrier(0);    // fence prior ds_reads vs this stage
    stageKV(kt);
    const bool doA = (kt <= tA);          // wave-uniform
    f32x4 bvsB[4], bvsA[4];
#pragma unroll
    for (int j = 0; j < 4; ++j) bvsB[j] = *(const f32x4*)(BpB + kt * 32 + 8 * j);
    if (doA) {
#pragma unroll
      for (int j = 0; j < 4; ++j) bvsA[j] = *(const f32x4*)(BpA + kt * 32 + 8 * j);
    }
    asm volatile("s_waitcnt vmcnt(0)" ::: "memory");  // stage + bias landed
    __builtin_amdgcn_sched_barrier(0);

    const unsigned char* Ksh = Kdst;
    const unsigned char* Vsh = Vdst;
    bf16x8 kf[4];
#pragma unroll
    for (int c = 0; c < 4; ++c)
      kf[c] = *(const bf16x8*)(Ksh + ql * 128 + (((hi + 2 * c) ^ (ql & 7)) << 4));
    const int vb = ((ql >> 4) << 10) + ((ql & 15) << 6);
    bf16x8 va00 = *(const bf16x8*)(Vsh + vb + (((hi) ^ (ql & 3)) << 4));
    bf16x8 va01 = *(const bf16x8*)(Vsh + vb + (((hi + 2) ^ (ql & 3)) << 4));
    bf16x8 va10 = *(const bf16x8*)(Vsh + 2048 + vb + (((hi) ^ (ql & 3)) << 4));
    bf16x8 va11 = *(const bf16x8*)(Vsh + 2048 + vb + (((hi + 2) ^ (ql & 3)) << 4));

    attn_chain(qfB, bvsB, kf[0], kf[1], kf[2], kf[3], va00, va01, va10, va11,
               kt == tB, ql, hi, oB0, oB1, plsB);
    if (doA) {
      attn_chain(qfA, bvsA, kf[0], kf[1], kf[2], kf[3], va00, va01, va10, va11,
                 kt == tA, ql, hi, oA0, oA1, plsA);
    }
  }

  // ---- cross-wave combine epilogue (aliased onto staging LDS) ----
  __syncthreads();                          // all waves done with staging LDS
  float* ldsF = (float*)lds;
  float* lsumbuf = ldsF + 8448;             // [2][256]
  float* rowinv = ldsF + 8960;              // [2][32]
  lsumbuf[(w * 2 + hi) * 32 + ql] = plsA;
  lsumbuf[256 + (w * 2 + hi) * 32 + ql] = plsB;
  if (w >= 2) {
    float* OA = ldsF + (w - 2) * 2112;          // Obuf[tile0][w-2]
    float* OB = ldsF + (2 + (w - 2)) * 2112;    // Obuf[tile1][w-2]
#pragma unroll
    for (int reg = 0; reg < 16; ++reg) {
      int d0 = (reg & 3) + 8 * (reg >> 2) + 4 * hi;
      OA[d0 * 33 + ql] = oA0[reg];
      OA[(d0 + 32) * 33 + ql] = oA1[reg];
      OB[d0 * 33 + ql] = oB0[reg];
      OB[(d0 + 32) * 33 + ql] = oB1[reg];
    }
  }
  __syncthreads();
  if (w < 2) {
    float* OA = ldsF + w * 2112;
    float* OB = ldsF + (2 + w) * 2112;
#pragma unroll
    for (int reg = 0; reg < 16; ++reg) {
      int d0 = (reg & 3) + 8 * (reg >> 2) + 4 * hi;
      OA[d0 * 33 + ql] += oA0[reg];
      OA[(d0 + 32) * 33 + ql] += oA1[reg];
      OB[d0 * 33 + ql] += oB0[reg];
      OB[(d0 + 32) * 33 + ql] += oB1[reg];
    }
  }
  __syncthreads();
  if (tid < 64) {
    int t = tid >> 5, q = tid & 31;
    float s = 0.f;
#pragma unroll
    for (int j = 0; j < 8; ++j) s += lsumbuf[t * 256 + j * 32 + q];
    rowinv[t * 32 + q] = frcp(s);
  }
  __syncthreads();
  // final write: d fastest -> 128B-contiguous global stores
#pragma unroll
  for (int it = 0; it < 16; ++it) {
    int i = it * 256 + tid;
    int t = i >> 11;
    int rem = i & 2047;
    int q = rem >> 6, d = rem & 63;
    float val = (ldsF[t * 4224 + d * 33 + q] + ldsF[t * 4224 + 2112 + d * 33 + q])
                * rowinv[t * 32 + q];
    int row = b * 2048 + (t ? q0B : q0A) + q;
    Ob[(size_t)row * 1024 + h * 64 + d] = f2b(val);
  }
}

extern "C" void kernel_launch(void* const* d_in, const int* in_sizes, int n_in,
                              void* d_out, int out_size, void* d_ws, size_t ws_size,
                              hipStream_t stream) {
  (void)in_sizes; (void)n_in; (void)out_size; (void)ws_size;
  const float* inp  = (const float*)d_in[0];
  const float* bias = (const float*)d_in[1];
  // d_in[2] = attn_mask (causal, recomputed in-kernel)
  const float* wq = (const float*)d_in[3];
  const float* wk = (const float*)d_in[4];
  const float* wv = (const float*)d_in[5];
  const float* wo = (const float*)d_in[6];
  float* out = (float*)d_out;

  unsigned short* Xb   = (unsigned short*)d_ws;     // 4096x1024 bf16
  unsigned short* Wcat = Xb + 4194304;              // 4 x 1024x1024 bf16
  unsigned short* Qb   = Wcat + 4194304;            // 4096x1024
  unsigned short* Kb   = Qb + 4194304;              // 4096x1024
  unsigned short* Vt   = Kb + 4194304;              // (2*16*64) x 2048
  unsigned short* Ob   = Vt + 4194304;              // 4096x1024

  convert_kernel<<<8192, 256, 0, stream>>>(inp, wq, wk, wv, wo, Xb, Wcat);
  gemm_qkv<<<dim3(32, 8, 3), dim3(256), 0, stream>>>(Xb, Wcat, Qb, Kb, Vt);
  attn_fwd<<<1024, 256, 0, stream>>>(Qb, Kb, Vt, bias, Ob);
  gemm_out<<<dim3(32, 8, 1), dim3(256), 0, stream>>>(Ob, Wcat + 3 * 1048576, out);
}

// Round 14
// 142.392 us; speedup vs baseline: 1.5902x; 1.5902x over previous
//
#include <hip/hip_runtime.h>
#include <hip/hip_bf16.h>

#define GK 1024

typedef __attribute__((ext_vector_type(8))) short bf16x8;
typedef __attribute__((ext_vector_type(4))) float f32x4;
typedef __attribute__((ext_vector_type(16))) float f32x16;
typedef __attribute__((ext_vector_type(4))) unsigned short ushort4v;

__device__ __forceinline__ f32x4 mfma16(bf16x8 a, bf16x8 b, f32x4 c) {
  return __builtin_amdgcn_mfma_f32_16x16x32_bf16(a, b, c, 0, 0, 0);
}
__device__ __forceinline__ f32x16 mfma32(bf16x8 a, bf16x8 b, f32x16 c) {
  return __builtin_amdgcn_mfma_f32_32x32x16_bf16(a, b, c, 0, 0, 0);
}

__device__ __forceinline__ unsigned short f2b(float f) {
  union { float f; unsigned int u; } x; x.f = f;
  return (unsigned short)((x.u + 0x7fffu + ((x.u >> 16) & 1u)) >> 16);
}

// packed f32x2 -> bf16x2 (RNE); lowers to v_cvt_pk_bf16_f32
__device__ __forceinline__ unsigned int pk2(float lo, float hi) {
  float2 f; f.x = lo; f.y = hi;
  __hip_bfloat162 t = __float22bfloat162_rn(f);
  union { __hip_bfloat162 b; unsigned int u; } c; c.b = t;
  return c.u;
}

__device__ __forceinline__ float fexp2(float x) {
#if __has_builtin(__builtin_amdgcn_exp2f)
  return __builtin_amdgcn_exp2f(x);
#else
  return exp2f(x);
#endif
}
__device__ __forceinline__ float frcp(float x) {
#if __has_builtin(__builtin_amdgcn_rcpf)
  return __builtin_amdgcn_rcpf(x);
#else
  return 1.0f / x;
#endif
}

// async global->LDS, 16B per lane; LDS dest = wave-uniform base + lane*16
__device__ __forceinline__ void gl_lds16(const void* g, void* l) {
  __builtin_amdgcn_global_load_lds(
      (const __attribute__((address_space(1))) unsigned int*)g,
      (__attribute__((address_space(3))) unsigned int*)l, 16, 0, 0);
}

// ---------------- convert fp32 -> bf16 (inp + 4 weight mats) ----------------
__global__ __launch_bounds__(256) void convert_kernel(
    const float* __restrict__ inp,
    const float* __restrict__ wq, const float* __restrict__ wk,
    const float* __restrict__ wv, const float* __restrict__ wo,
    unsigned short* __restrict__ Xb, unsigned short* __restrict__ Wcat)
{
  const size_t XN = (size_t)4194304;  // 2*2048*1024
  size_t i = ((size_t)blockIdx.x * 256 + threadIdx.x) * 4;
  const float* src; unsigned short* dst; size_t off;
  if (i < XN) {
    src = inp; dst = Xb; off = i;
  } else {
    size_t j = i - XN;
    int w = (int)(j >> 20);
    off = j & 1048575u;
    src = (w == 0) ? wq : (w == 1) ? wk : (w == 2) ? wv : wo;
    dst = Wcat + ((size_t)w << 20);
  }
  f32x4 v = *(const f32x4*)(src + off);
  ushort4v o;
#pragma unroll
  for (int t = 0; t < 4; ++t) o[t] = f2b(v[t]);
  *(ushort4v*)(dst + off) = o;
}

// ------------- GEMM mainloop via global_load_lds (m97 pattern) --------------
// R8-proven form: 16KB LDS, two barriers per K-step. (The 1-barrier dbuf
// variant measured ~5us slower overall: its end-of-iter barrier drains the
// just-issued prefetch anyway, and 2x LDS cost occupancy.)
__device__ __forceinline__ void gemm_mainloop(
    const unsigned short* __restrict__ A, const unsigned short* __restrict__ Wt,
    int m0, int n0, int tid, unsigned short* As, unsigned short* Bs,
    f32x4 (&acc)[4][4])
{
  const int lane = tid & 63;
  const int wave = tid >> 6;
  const int wr = wave >> 1, wc = wave & 1;
  const int lq = lane & 15, g = lane >> 4;

  const int r_in = lane >> 2;          // 0..15
  const int c8 = (lane & 3) * 8;       // element col: 0,8,16,24

  const unsigned short* Ap0 = A + (size_t)(m0 + wave * 32 + r_in) * GK + c8;
  const unsigned short* Ap1 = Ap0 + (size_t)16 * GK;
  const unsigned short* Wp0 = Wt + (size_t)(n0 + wave * 32 + r_in) * GK + c8;
  const unsigned short* Wp1 = Wp0 + (size_t)16 * GK;
  unsigned short* As0 = As + wave * 1024;   // elements (2KB per wave)
  unsigned short* Bs0 = Bs + wave * 1024;

  for (int kt = 0; kt < GK / 32; ++kt) {
    const int k0 = kt * 32;
    __syncthreads();                       // prev tile's reads done
    gl_lds16(Ap0 + k0, As0);
    gl_lds16(Ap1 + k0, As0 + 512);
    gl_lds16(Wp0 + k0, Bs0);
    gl_lds16(Wp1 + k0, Bs0 + 512);
    __syncthreads();                       // drains vmcnt -> LDS valid
    bf16x8 af[4], bfr[4];
#pragma unroll
    for (int i = 0; i < 4; ++i)
      af[i] = *(const bf16x8*)(As + (wr * 64 + i * 16 + lq) * 32 + g * 8);
#pragma unroll
    for (int j = 0; j < 4; ++j)
      bfr[j] = *(const bf16x8*)(Bs + (wc * 64 + j * 16 + lq) * 32 + g * 8);
#pragma unroll
    for (int i = 0; i < 4; ++i)
#pragma unroll
      for (int j = 0; j < 4; ++j)
        acc[i][j] = mfma16(af[i], bfr[j], acc[i][j]);
  }
}

// ---------------- QKV projection GEMM (z: 0=Q, 1=K, 2=V-transposed) ----------
__global__ __launch_bounds__(256) void gemm_qkv(
    const unsigned short* __restrict__ X, const unsigned short* __restrict__ Wcat,
    unsigned short* __restrict__ Qb, unsigned short* __restrict__ Kb,
    unsigned short* __restrict__ Vt)
{
  __shared__ unsigned short As[4096];
  __shared__ unsigned short Bs[4096];
  f32x4 acc[4][4];
#pragma unroll
  for (int i = 0; i < 4; ++i)
#pragma unroll
    for (int j = 0; j < 4; ++j) acc[i][j] = (f32x4){0.f, 0.f, 0.f, 0.f};

  const int z = blockIdx.z;
  const int m0 = blockIdx.x * 128, n0 = blockIdx.y * 128;
  gemm_mainloop(X, Wcat + ((size_t)z << 20), m0, n0, (int)threadIdx.x, As, Bs, acc);

  const int lane = threadIdx.x & 63;
  const int wave = threadIdx.x >> 6;
  const int wr = wave >> 1, wc = wave & 1, lq = lane & 15, g = lane >> 4;

  if (z < 2) {
    unsigned short* C = z ? Kb : Qb;
#pragma unroll
    for (int i = 0; i < 4; ++i)
#pragma unroll
      for (int j = 0; j < 4; ++j) {
        int col = n0 + wc * 64 + j * 16 + lq;
#pragma unroll
        for (int r = 0; r < 4; ++r) {
          int row = m0 + wr * 64 + i * 16 + g * 4 + r;
          C[(size_t)row * 1024 + col] = f2b(acc[i][j][r]);
        }
      }
  } else {
    // V transposed: Vt[(b*1024 + n)][s], n = h*64+dk
#pragma unroll
    for (int i = 0; i < 4; ++i)
#pragma unroll
      for (int j = 0; j < 4; ++j) {
        int col = n0 + wc * 64 + j * 16 + lq;
        int row0 = m0 + wr * 64 + i * 16 + g * 4;
        int b = row0 >> 11;
        int s = row0 & 2047;
        ushort4v pv;
#pragma unroll
        for (int r = 0; r < 4; ++r) pv[r] = f2b(acc[i][j][r]);
        *(ushort4v*)(Vt + (size_t)(b * 1024 + col) * 2048 + s) = pv;
      }
  }
}

// ---------------- output projection GEMM (fp32 out) ----------------
__global__ __launch_bounds__(256) void gemm_out(
    const unsigned short* __restrict__ Ob, const unsigned short* __restrict__ Wo,
    float* __restrict__ out)
{
  __shared__ unsigned short As[4096];
  __shared__ unsigned short Bs[4096];
  f32x4 acc[4][4];
#pragma unroll
  for (int i = 0; i < 4; ++i)
#pragma unroll
    for (int j = 0; j < 4; ++j) acc[i][j] = (f32x4){0.f, 0.f, 0.f, 0.f};

  const int m0 = blockIdx.x * 128, n0 = blockIdx.y * 128;
  gemm_mainloop(Ob, Wo, m0, n0, (int)threadIdx.x, As, Bs, acc);

  const int lane = threadIdx.x & 63;
  const int wave = threadIdx.x >> 6;
  const int wr = wave >> 1, wc = wave & 1, lq = lane & 15, g = lane >> 4;
#pragma unroll
  for (int i = 0; i < 4; ++i)
#pragma unroll
    for (int j = 0; j < 4; ++j) {
      int col = n0 + wc * 64 + j * 16 + lq;
#pragma unroll
      for (int r = 0; r < 4; ++r) {
        int row = m0 + wr * 64 + i * 16 + g * 4 + r;
        out[(size_t)row * 1024 + col] = acc[i][j][r];
      }
    }
}

// ---------------- attention tile chain: softcap + pack + PV ----------------
// Poly-tanh softcap: p = exp2(C1*tanh(y) - C1), y = (raw/8 + bias)/30.
__device__ __forceinline__ void attn_chain(
    const bf16x8 (&qf)[4], const f32x4 (&bvs)[4],
    bf16x8 kf0, bf16x8 kf1, bf16x8 kf2, bf16x8 kf3,
    bf16x8 va00, bf16x8 va01, bf16x8 va10, bf16x8 va11,
    bool msk, int ql, int hi,
    f32x16& o0, f32x16& o1, float& pls)
{
  const float INV30 = 0.033333333333f;
  const float C3 = -0.333333333f, C5 = 0.133333333f;
  const float C1 = 43.28085122666891f;   // 30*log2(e)

  f32x16 st = {0.f,0.f,0.f,0.f,0.f,0.f,0.f,0.f,0.f,0.f,0.f,0.f,0.f,0.f,0.f,0.f};
  st = mfma32(kf0, qf[0], st);
  st = mfma32(kf1, qf[1], st);
  st = mfma32(kf2, qf[2], st);
  st = mfma32(kf3, qf[3], st);

  float p[16];
#pragma unroll
  for (int reg = 0; reg < 16; ++reg) {
    float v = fmaf(st[reg], 0.125f, bvs[reg >> 2][reg & 3]);
    float y = v * INV30;
    float y2 = y * y;
    float t = y * fmaf(y2, fmaf(y2, C5, C3), 1.0f);
    p[reg] = fexp2(fmaf(t, C1, -C1));
  }
  if (msk) {
#pragma unroll
    for (int reg = 0; reg < 16; ++reg) {
      int krow = (reg & 3) + 8 * (reg >> 2) + 4 * hi;
      p[reg] = (krow <= ql) ? p[reg] : 0.f;
    }
  }
  float a0 = (p[0] + p[1]) + (p[2] + p[3]);
  float a1 = (p[4] + p[5]) + (p[6] + p[7]);
  float a2 = (p[8] + p[9]) + (p[10] + p[11]);
  float a3 = (p[12] + p[13]) + (p[14] + p[15]);
  pls += (a0 + a1) + (a2 + a3);

  unsigned int wv[8];
#pragma unroll
  for (int j = 0; j < 8; ++j) wv[j] = pk2(p[2 * j], p[2 * j + 1]);
  unsigned int x0 = hi ? wv[0] : wv[2], x1 = hi ? wv[1] : wv[3];
  x0 = __shfl_xor(x0, 32); x1 = __shfl_xor(x1, 32);
  unsigned int y0 = hi ? wv[4] : wv[6], y1 = hi ? wv[5] : wv[7];
  y0 = __shfl_xor(y0, 32); y1 = __shfl_xor(y1, 32);
  union { unsigned int u[4]; bf16x8 v; } B0, B1;
  B0.u[0] = hi ? x0 : wv[0]; B0.u[1] = hi ? x1 : wv[1];
  B0.u[2] = hi ? wv[2] : x0; B0.u[3] = hi ? wv[3] : x1;
  B1.u[0] = hi ? y0 : wv[4]; B1.u[1] = hi ? y1 : wv[5];
  B1.u[2] = hi ? wv[6] : y0; B1.u[3] = hi ? wv[7] : y1;

  o0 = mfma32(va00, B0.v, o0);
  o0 = mfma32(va01, B1.v, o0);
  o1 = mfma32(va10, B0.v, o1);
  o1 = mfma32(va11, B1.v, o1);
}

// ---- fused flash attention: symmetric q-pair, KVBLK=64 pair rounds ----
// R11 structure (69.4us best) with TWO k-tiles per round: wave w handles
// tile-pairs p = w (mod 4), staging both tiles (16KB/wave region) + all four
// bias tile-sets, then ONE vmcnt(0) per pair -> waits per tile halve, compute
// per wait doubles (stall fraction ~35% -> ~20%). LDS 64KB/block is free
// (VGPR caps at 2 blocks/CU). Register ladder (measured): (256,2)->108 arch,
// no spill; (256,3)->84, partial spill, 2.3x slower; (256,4)->64, acc spill,
// 2.7x slower. NEVER raise the bound. Go/no-go: WRITE_SIZE ~8MB.
__global__ __launch_bounds__(256, 2) void attn_fwd(
    const unsigned short* __restrict__ Qb, const unsigned short* __restrict__ Kb,
    const unsigned short* __restrict__ Vt, const float* __restrict__ bias,
    unsigned short* __restrict__ Ob)
{
  __shared__ __attribute__((aligned(16))) unsigned char lds[65536];

  const int tid = (int)threadIdx.x;
  const int lane = tid & 63;
  const int w = tid >> 6;
  // XCD affinity: xcd = bid&7 owns heads [4*xcd, 4*xcd+4)
  const int bid = (int)blockIdx.x;
  const int bh = (bid & 7) * 4 + ((bid >> 3) & 3);
  const int qp = bid >> 5;                 // 0..31
  const int b = bh >> 4, h = bh & 15;
  const int tA = qp, tB = 63 - qp;
  const int q0A = tA * 32, q0B = tB * 32;
  const int ql = lane & 31;
  const int hi = lane >> 5;

  // ---- Q fragments (one-time gather) ----
  const unsigned short* QpA = Qb + (size_t)(b * 2048 + q0A + ql) * 1024 + h * 64 + 8 * hi;
  const unsigned short* QpB = Qb + (size_t)(b * 2048 + q0B + ql) * 1024 + h * 64 + 8 * hi;
  bf16x8 qfA[4], qfB[4];
#pragma unroll
  for (int c = 0; c < 4; ++c) {
    qfA[c] = *(const bf16x8*)(QpA + 16 * c);
    qfB[c] = *(const bf16x8*)(QpB + 16 * c);
  }

  // ---- per-lane staging sources (inverse-swizzled, rule #21) ----
  const unsigned short* KsrcL = Kb + (size_t)(b * 2048 + (lane >> 3)) * 1024
                                + h * 64 + (((lane & 7) ^ ((lane >> 3) & 7)) << 3);
  const unsigned short* VsrcL = Vt + (size_t)(bh * 64 + (lane >> 2)) * 2048
                                + (((lane & 3) ^ ((lane >> 2) & 3)) << 3);
  unsigned char* const Kdst = lds + w * 16384;  // per tile: K 4KB + V 4KB

  const float* BpA = bias + (size_t)b * 4194304 + (size_t)(q0A + ql) * 2048 + 4 * hi;
  const float* BpB = bias + (size_t)b * 4194304 + (size_t)(q0B + ql) * 2048 + 4 * hi;

  float plsA = 0.f, plsB = 0.f;
  f32x16 oA0 = {0.f,0.f,0.f,0.f,0.f,0.f,0.f,0.f,0.f,0.f,0.f,0.f,0.f,0.f,0.f,0.f};
  f32x16 oA1 = oA0, oB0 = oA0, oB1 = oA0;

  auto stageKV = [&](int kt, int off) {
    unsigned char* Kd = Kdst + off;
    unsigned char* Vd = Kd + 4096;
#pragma unroll
    for (int j = 0; j < 4; ++j)
      gl_lds16(KsrcL + (size_t)kt * 32768 + j * 8192, Kd + j * 1024);
#pragma unroll
    for (int j = 0; j < 4; ++j)
      gl_lds16(VsrcL + (size_t)j * 32768 + kt * 32, Vd + j * 1024);
  };
  auto ldfrags = [&](int off, bf16x8 (&kf)[4], bf16x8& va00, bf16x8& va01,
                     bf16x8& va10, bf16x8& va11) {
    const unsigned char* Ksh = Kdst + off;
    const unsigned char* Vsh = Ksh + 4096;
#pragma unroll
    for (int c = 0; c < 4; ++c)
      kf[c] = *(const bf16x8*)(Ksh + ql * 128 + (((hi + 2 * c) ^ (ql & 7)) << 4));
    const int vb = ((ql >> 4) << 10) + ((ql & 15) << 6);
    va00 = *(const bf16x8*)(Vsh + vb + (((hi) ^ (ql & 3)) << 4));
    va01 = *(const bf16x8*)(Vsh + vb + (((hi + 2) ^ (ql & 3)) << 4));
    va10 = *(const bf16x8*)(Vsh + 2048 + vb + (((hi) ^ (ql & 3)) << 4));
    va11 = *(const bf16x8*)(Vsh + 2048 + vb + (((hi + 2) ^ (ql & 3)) << 4));
  };

  for (int kt0 = 2 * w; kt0 <= tB; kt0 += 8) {
    const int kt1 = kt0 + 1;                 // kt0 even <= tB -> kt1 <= 63: stage-safe
    const bool doB1 = (kt1 <= tB);
    const bool doA0 = (kt0 <= tA);
    const bool doA1 = (kt1 <= tA);

    __builtin_amdgcn_sched_barrier(0);       // prev rounds' ds_reads stay above
    stageKV(kt0, 0);
    stageKV(kt1, 8192);
    f32x4 bB0[4], bB1[4], bA0[4], bA1[4];
#pragma unroll
    for (int j = 0; j < 4; ++j) bB0[j] = *(const f32x4*)(BpB + kt0 * 32 + 8 * j);
    if (doB1) {
#pragma unroll
      for (int j = 0; j < 4; ++j) bB1[j] = *(const f32x4*)(BpB + kt1 * 32 + 8 * j);
    }
    if (doA0) {
#pragma unroll
      for (int j = 0; j < 4; ++j) bA0[j] = *(const f32x4*)(BpA + kt0 * 32 + 8 * j);
    }
    if (doA1) {
#pragma unroll
      for (int j = 0; j < 4; ++j) bA1[j] = *(const f32x4*)(BpA + kt1 * 32 + 8 * j);
    }
    asm volatile("s_waitcnt vmcnt(0)" ::: "memory");  // stages + bias landed
    __builtin_amdgcn_sched_barrier(0);       // rule #18: fence before ds_reads

    {  // tile 0
      bf16x8 kf[4], va00, va01, va10, va11;
      ldfrags(0, kf, va00, va01, va10, va11);
      attn_chain(qfB, bB0, kf[0], kf[1], kf[2], kf[3], va00, va01, va10, va11,
                 kt0 == tB, ql, hi, oB0, oB1, plsB);
      if (doA0)
        attn_chain(qfA, bA0, kf[0], kf[1], kf[2], kf[3], va00, va01, va10, va11,
                   kt0 == tA, ql, hi, oA0, oA1, plsA);
    }
    if (doB1) {  // tile 1
      bf16x8 kf[4], va00, va01, va10, va11;
      ldfrags(8192, kf, va00, va01, va10, va11);
      attn_chain(qfB, bB1, kf[0], kf[1], kf[2], kf[3], va00, va01, va10, va11,
                 kt1 == tB, ql, hi, oB0, oB1, plsB);
      if (doA1)
        attn_chain(qfA, bA1, kf[0], kf[1], kf[2], kf[3], va00, va01, va10, va11,
                   kt1 == tA, ql, hi, oA0, oA1, plsA);
    }
  }

  // ---- cross-wave combine epilogue (aliased onto staging LDS) ----
  __syncthreads();                          // all waves done with staging LDS
  float* ldsF = (float*)lds;
  float* lsumbuf = ldsF + 8448;             // [2][256]
  float* rowinv = ldsF + 8960;              // [2][32]
  lsumbuf[(w * 2 + hi) * 32 + ql] = plsA;
  lsumbuf[256 + (w * 2 + hi) * 32 + ql] = plsB;
  if (w >= 2) {
    float* OA = ldsF + (w - 2) * 2112;          // Obuf[tile0][w-2]
    float* OB = ldsF + (2 + (w - 2)) * 2112;    // Obuf[tile1][w-2]
#pragma unroll
    for (int reg = 0; reg < 16; ++reg) {
      int d0 = (reg & 3) + 8 * (reg >> 2) + 4 * hi;
      OA[d0 * 33 + ql] = oA0[reg];
      OA[(d0 + 32) * 33 + ql] = oA1[reg];
      OB[d0 * 33 + ql] = oB0[reg];
      OB[(d0 + 32) * 33 + ql] = oB1[reg];
    }
  }
  __syncthreads();
  if (w < 2) {
    float* OA = ldsF + w * 2112;
    float* OB = ldsF + (2 + w) * 2112;
#pragma unroll
    for (int reg = 0; reg < 16; ++reg) {
      int d0 = (reg & 3) + 8 * (reg >> 2) + 4 * hi;
      OA[d0 * 33 + ql] += oA0[reg];
      OA[(d0 + 32) * 33 + ql] += oA1[reg];
      OB[d0 * 33 + ql] += oB0[reg];
      OB[(d0 + 32) * 33 + ql] += oB1[reg];
    }
  }
  __syncthreads();
  if (tid < 64) {
    int t = tid >> 5, q = tid & 31;
    float s = 0.f;
#pragma unroll
    for (int j = 0; j < 8; ++j) s += lsumbuf[t * 256 + j * 32 + q];
    rowinv[t * 32 + q] = frcp(s);
  }
  __syncthreads();
  // final write: d fastest -> 128B-contiguous global stores
#pragma unroll
  for (int it = 0; it < 16; ++it) {
    int i = it * 256 + tid;
    int t = i >> 11;
    int rem = i & 2047;
    int q = rem >> 6, d = rem & 63;
    float val = (ldsF[t * 4224 + d * 33 + q] + ldsF[t * 4224 + 2112 + d * 33 + q])
                * rowinv[t * 32 + q];
    int row = b * 2048 + (t ? q0B : q0A) + q;
    Ob[(size_t)row * 1024 + h * 64 + d] = f2b(val);
  }
}

extern "C" void kernel_launch(void* const* d_in, const int* in_sizes, int n_in,
                              void* d_out, int out_size, void* d_ws, size_t ws_size,
                              hipStream_t stream) {
  (void)in_sizes; (void)n_in; (void)out_size; (void)ws_size;
  const float* inp  = (const float*)d_in[0];
  const float* bias = (const float*)d_in[1];
  // d_in[2] = attn_mask (causal, recomputed in-kernel)
  const float* wq = (const float*)d_in[3];
  const float* wk = (const float*)d_in[4];
  const float* wv = (const float*)d_in[5];
  const float* wo = (const float*)d_in[6];
  float* out = (float*)d_out;

  unsigned short* Xb   = (unsigned short*)d_ws;     // 4096x1024 bf16
  unsigned short* Wcat = Xb + 4194304;              // 4 x 1024x1024 bf16
  unsigned short* Qb   = Wcat + 4194304;            // 4096x1024
  unsigned short* Kb   = Qb + 4194304;              // 4096x1024
  unsigned short* Vt   = Kb + 4194304;              // (2*16*64) x 2048
  unsigned short* Ob   = Vt + 4194304;              // 4096x1024

  convert_kernel<<<8192, 256, 0, stream>>>(inp, wq, wk, wv, wo, Xb, Wcat);
  gemm_qkv<<<dim3(32, 8, 3), dim3(256), 0, stream>>>(Xb, Wcat, Qb, Kb, Vt);
  attn_fwd<<<1024, 256, 0, stream>>>(Qb, Kb, Vt, bias, Ob);
  gemm_out<<<dim3(32, 8, 1), dim3(256), 0, stream>>>(Ob, Wcat + 3 * 1048576, out);
}

// Round 16
// 140.895 us; speedup vs baseline: 1.6071x; 1.0106x over previous
//
#include <hip/hip_runtime.h>
#include <hip/hip_bf16.h>

#define GK 1024

typedef __attribute__((ext_vector_type(8))) short bf16x8;
typedef __attribute__((ext_vector_type(4))) float f32x4;
typedef __attribute__((ext_vector_type(16))) float f32x16;
typedef __attribute__((ext_vector_type(4))) unsigned short ushort4v;
typedef __attribute__((ext_vector_type(2))) unsigned int uint2v;

__device__ __forceinline__ f32x4 mfma16(bf16x8 a, bf16x8 b, f32x4 c) {
  return __builtin_amdgcn_mfma_f32_16x16x32_bf16(a, b, c, 0, 0, 0);
}
__device__ __forceinline__ f32x16 mfma32(bf16x8 a, bf16x8 b, f32x16 c) {
  return __builtin_amdgcn_mfma_f32_32x32x16_bf16(a, b, c, 0, 0, 0);
}

__device__ __forceinline__ unsigned short f2b(float f) {
  union { float f; unsigned int u; } x; x.f = f;
  return (unsigned short)((x.u + 0x7fffu + ((x.u >> 16) & 1u)) >> 16);
}

// packed f32x2 -> bf16x2 (RNE); lowers to v_cvt_pk_bf16_f32
__device__ __forceinline__ unsigned int pk2(float lo, float hi) {
  float2 f; f.x = lo; f.y = hi;
  __hip_bfloat162 t = __float22bfloat162_rn(f);
  union { __hip_bfloat162 b; unsigned int u; } c; c.b = t;
  return c.u;
}

__device__ __forceinline__ float fexp2(float x) {
#if __has_builtin(__builtin_amdgcn_exp2f)
  return __builtin_amdgcn_exp2f(x);
#else
  return exp2f(x);
#endif
}
__device__ __forceinline__ float frcp(float x) {
#if __has_builtin(__builtin_amdgcn_rcpf)
  return __builtin_amdgcn_rcpf(x);
#else
  return 1.0f / x;
#endif
}

// async global->LDS, 16B per lane; LDS dest = wave-uniform base + lane*16
__device__ __forceinline__ void gl_lds16(const void* g, void* l) {
  __builtin_amdgcn_global_load_lds(
      (const __attribute__((address_space(1))) unsigned int*)g,
      (__attribute__((address_space(3))) unsigned int*)l, 16, 0, 0);
}

// ---------------- convert fp32 -> bf16 (inp + 4 weight mats) ----------------
__global__ __launch_bounds__(256) void convert_kernel(
    const float* __restrict__ inp,
    const float* __restrict__ wq, const float* __restrict__ wk,
    const float* __restrict__ wv, const float* __restrict__ wo,
    unsigned short* __restrict__ Xb, unsigned short* __restrict__ Wcat)
{
  const size_t XN = (size_t)4194304;  // 2*2048*1024
  size_t i = ((size_t)blockIdx.x * 256 + threadIdx.x) * 4;
  const float* src; unsigned short* dst; size_t off;
  if (i < XN) {
    src = inp; dst = Xb; off = i;
  } else {
    size_t j = i - XN;
    int w = (int)(j >> 20);
    off = j & 1048575u;
    src = (w == 0) ? wq : (w == 1) ? wk : (w == 2) ? wv : wo;
    dst = Wcat + ((size_t)w << 20);
  }
  f32x4 v = *(const f32x4*)(src + off);
  ushort4v o;
#pragma unroll
  for (int t = 0; t < 4; ++t) o[t] = f2b(v[t]);
  *(ushort4v*)(dst + off) = o;
}

// ------------- GEMM mainloop via global_load_lds (m97 pattern) --------------
// R8-proven form: 16KB LDS, two barriers per K-step. (The 1-barrier dbuf
// variant measured ~5us slower overall: its end-of-iter barrier drains the
// just-issued prefetch anyway, and 2x LDS cost occupancy.)
__device__ __forceinline__ void gemm_mainloop(
    const unsigned short* __restrict__ A, const unsigned short* __restrict__ Wt,
    int m0, int n0, int tid, unsigned short* As, unsigned short* Bs,
    f32x4 (&acc)[4][4])
{
  const int lane = tid & 63;
  const int wave = tid >> 6;
  const int wr = wave >> 1, wc = wave & 1;
  const int lq = lane & 15, g = lane >> 4;

  const int r_in = lane >> 2;          // 0..15
  const int c8 = (lane & 3) * 8;       // element col: 0,8,16,24

  const unsigned short* Ap0 = A + (size_t)(m0 + wave * 32 + r_in) * GK + c8;
  const unsigned short* Ap1 = Ap0 + (size_t)16 * GK;
  const unsigned short* Wp0 = Wt + (size_t)(n0 + wave * 32 + r_in) * GK + c8;
  const unsigned short* Wp1 = Wp0 + (size_t)16 * GK;
  unsigned short* As0 = As + wave * 1024;   // elements (2KB per wave)
  unsigned short* Bs0 = Bs + wave * 1024;

  for (int kt = 0; kt < GK / 32; ++kt) {
    const int k0 = kt * 32;
    __syncthreads();                       // prev tile's reads done
    gl_lds16(Ap0 + k0, As0);
    gl_lds16(Ap1 + k0, As0 + 512);
    gl_lds16(Wp0 + k0, Bs0);
    gl_lds16(Wp1 + k0, Bs0 + 512);
    __syncthreads();                       // drains vmcnt -> LDS valid
    bf16x8 af[4], bfr[4];
#pragma unroll
    for (int i = 0; i < 4; ++i)
      af[i] = *(const bf16x8*)(As + (wr * 64 + i * 16 + lq) * 32 + g * 8);
#pragma unroll
    for (int j = 0; j < 4; ++j)
      bfr[j] = *(const bf16x8*)(Bs + (wc * 64 + j * 16 + lq) * 32 + g * 8);
#pragma unroll
    for (int i = 0; i < 4; ++i)
#pragma unroll
      for (int j = 0; j < 4; ++j)
        acc[i][j] = mfma16(af[i], bfr[j], acc[i][j]);
  }
}

// ---------------- QKV projection GEMM (z: 0=Q, 1=K, 2=V-transposed) ----------
__global__ __launch_bounds__(256) void gemm_qkv(
    const unsigned short* __restrict__ X, const unsigned short* __restrict__ Wcat,
    unsigned short* __restrict__ Qb, unsigned short* __restrict__ Kb,
    unsigned short* __restrict__ Vt)
{
  __shared__ unsigned short As[4096];
  __shared__ unsigned short Bs[4096];
  f32x4 acc[4][4];
#pragma unroll
  for (int i = 0; i < 4; ++i)
#pragma unroll
    for (int j = 0; j < 4; ++j) acc[i][j] = (f32x4){0.f, 0.f, 0.f, 0.f};

  const int z = blockIdx.z;
  const int m0 = blockIdx.x * 128, n0 = blockIdx.y * 128;
  gemm_mainloop(X, Wcat + ((size_t)z << 20), m0, n0, (int)threadIdx.x, As, Bs, acc);

  const int lane = threadIdx.x & 63;
  const int wave = threadIdx.x >> 6;
  const int wr = wave >> 1, wc = wave & 1, lq = lane & 15, g = lane >> 4;

  if (z < 2) {
    unsigned short* C = z ? Kb : Qb;
#pragma unroll
    for (int i = 0; i < 4; ++i)
#pragma unroll
      for (int j = 0; j < 4; ++j) {
        int col = n0 + wc * 64 + j * 16 + lq;
#pragma unroll
        for (int r = 0; r < 4; ++r) {
          int row = m0 + wr * 64 + i * 16 + g * 4 + r;
          C[(size_t)row * 1024 + col] = f2b(acc[i][j][r]);
        }
      }
  } else {
    // V transposed: Vt[(b*1024 + n)][s], n = h*64+dk
#pragma unroll
    for (int i = 0; i < 4; ++i)
#pragma unroll
      for (int j = 0; j < 4; ++j) {
        int col = n0 + wc * 64 + j * 16 + lq;
        int row0 = m0 + wr * 64 + i * 16 + g * 4;
        int b = row0 >> 11;
        int s = row0 & 2047;
        ushort4v pv;
#pragma unroll
        for (int r = 0; r < 4; ++r) pv[r] = f2b(acc[i][j][r]);
        *(ushort4v*)(Vt + (size_t)(b * 1024 + col) * 2048 + s) = pv;
      }
  }
}

// ---------------- output projection GEMM (fp32 out) ----------------
__global__ __launch_bounds__(256) void gemm_out(
    const unsigned short* __restrict__ Ob, const unsigned short* __restrict__ Wo,
    float* __restrict__ out)
{
  __shared__ unsigned short As[4096];
  __shared__ unsigned short Bs[4096];
  f32x4 acc[4][4];
#pragma unroll
  for (int i = 0; i < 4; ++i)
#pragma unroll
    for (int j = 0; j < 4; ++j) acc[i][j] = (f32x4){0.f, 0.f, 0.f, 0.f};

  const int m0 = blockIdx.x * 128, n0 = blockIdx.y * 128;
  gemm_mainloop(Ob, Wo, m0, n0, (int)threadIdx.x, As, Bs, acc);

  const int lane = threadIdx.x & 63;
  const int wave = threadIdx.x >> 6;
  const int wr = wave >> 1, wc = wave & 1, lq = lane & 15, g = lane >> 4;
#pragma unroll
  for (int i = 0; i < 4; ++i)
#pragma unroll
    for (int j = 0; j < 4; ++j) {
      int col = n0 + wc * 64 + j * 16 + lq;
#pragma unroll
      for (int r = 0; r < 4; ++r) {
        int row = m0 + wr * 64 + i * 16 + g * 4 + r;
        out[(size_t)row * 1024 + col] = acc[i][j][r];
      }
    }
}

// ---------------- attention tile chain: softcap + pack + PV ----------------
// Poly-tanh softcap: p = exp2(C1*tanh(y) - C1), y = (raw/8 + bias)/30.
// T12: P-half exchange via permlane32_swap. Semantics (d.hi <-> s.lo):
//   swap(d,s): d = {d.lo, s.lo}, s = {d.hi, s.hi}.
// Proven shfl network needs u[0]={lo:w0.lo, hi:w2.lo}, u[2]={lo:w0.hi(hi-part
// at lo lanes), hi:w2.hi} -> swap(w0,w2) gives exactly w0->u[0], w2->u[2].
// (R15 bug: operands reversed -> misrouted k-slots, absmax 2.64.) Matches the
// T12 recipe: r = permlane32_swap(cvtpk(p0,p1), cvtpk(p4,p5)); r[0],r[1] used.
// T5: s_setprio(1) around MFMA clusters (barrier-free waves -> m191 regime).
__device__ __forceinline__ void attn_chain(
    const bf16x8 (&qf)[4], const f32x4 (&bvs)[4],
    bf16x8 kf0, bf16x8 kf1, bf16x8 kf2, bf16x8 kf3,
    bf16x8 va00, bf16x8 va01, bf16x8 va10, bf16x8 va11,
    bool msk, int ql, int hi,
    f32x16& o0, f32x16& o1, float& pls)
{
  const float INV30 = 0.033333333333f;
  const float C3 = -0.333333333f, C5 = 0.133333333f;
  const float C1 = 43.28085122666891f;   // 30*log2(e)

  f32x16 st = {0.f,0.f,0.f,0.f,0.f,0.f,0.f,0.f,0.f,0.f,0.f,0.f,0.f,0.f,0.f,0.f};
  __builtin_amdgcn_s_setprio(1);
  st = mfma32(kf0, qf[0], st);
  st = mfma32(kf1, qf[1], st);
  st = mfma32(kf2, qf[2], st);
  st = mfma32(kf3, qf[3], st);
  __builtin_amdgcn_s_setprio(0);

  float p[16];
#pragma unroll
  for (int reg = 0; reg < 16; ++reg) {
    float v = fmaf(st[reg], 0.125f, bvs[reg >> 2][reg & 3]);
    float y = v * INV30;
    float y2 = y * y;
    float t = y * fmaf(y2, fmaf(y2, C5, C3), 1.0f);
    p[reg] = fexp2(fmaf(t, C1, -C1));
  }
  if (msk) {
#pragma unroll
    for (int reg = 0; reg < 16; ++reg) {
      int krow = (reg & 3) + 8 * (reg >> 2) + 4 * hi;
      p[reg] = (krow <= ql) ? p[reg] : 0.f;
    }
  }
  float a0 = (p[0] + p[1]) + (p[2] + p[3]);
  float a1 = (p[4] + p[5]) + (p[6] + p[7]);
  float a2 = (p[8] + p[9]) + (p[10] + p[11]);
  float a3 = (p[12] + p[13]) + (p[14] + p[15]);
  pls += (a0 + a1) + (a2 + a3);

  unsigned int w0 = pk2(p[0], p[1]),  w1 = pk2(p[2], p[3]);
  unsigned int w2 = pk2(p[4], p[5]),  w3 = pk2(p[6], p[7]);
  unsigned int w4 = pk2(p[8], p[9]),  w5 = pk2(p[10], p[11]);
  unsigned int w6 = pk2(p[12], p[13]), w7 = pk2(p[14], p[15]);
  union { unsigned int u[4]; bf16x8 v; } B0, B1;
#if __has_builtin(__builtin_amdgcn_permlane32_swap)
  uint2v r02 = __builtin_amdgcn_permlane32_swap(w0, w2, false, false);
  uint2v r13 = __builtin_amdgcn_permlane32_swap(w1, w3, false, false);
  uint2v r46 = __builtin_amdgcn_permlane32_swap(w4, w6, false, false);
  uint2v r57 = __builtin_amdgcn_permlane32_swap(w5, w7, false, false);
  B0.u[0] = r02[0]; B0.u[1] = r13[0]; B0.u[2] = r02[1]; B0.u[3] = r13[1];
  B1.u[0] = r46[0]; B1.u[1] = r57[0]; B1.u[2] = r46[1]; B1.u[3] = r57[1];
#else
  unsigned int x0 = hi ? w0 : w2, x1 = hi ? w1 : w3;
  x0 = __shfl_xor(x0, 32); x1 = __shfl_xor(x1, 32);
  unsigned int y0 = hi ? w4 : w6, y1 = hi ? w5 : w7;
  y0 = __shfl_xor(y0, 32); y1 = __shfl_xor(y1, 32);
  B0.u[0] = hi ? x0 : w0; B0.u[1] = hi ? x1 : w1;
  B0.u[2] = hi ? w2 : x0; B0.u[3] = hi ? w3 : x1;
  B1.u[0] = hi ? y0 : w4; B1.u[1] = hi ? y1 : w5;
  B1.u[2] = hi ? w6 : y0; B1.u[3] = hi ? w7 : y1;
#endif

  __builtin_amdgcn_s_setprio(1);
  o0 = mfma32(va00, B0.v, o0);
  o0 = mfma32(va01, B1.v, o0);
  o1 = mfma32(va10, B0.v, o1);
  o1 = mfma32(va11, B1.v, o1);
  __builtin_amdgcn_s_setprio(0);
}

// ---- fused flash attention: symmetric q-pair, KVBLK=64 pair rounds ----
// Wave w handles tile-pairs p = w (mod 4): stage both tiles (16KB/wave) +
// four bias tile-sets, ONE vmcnt(0) per pair. LDS 64KB/block free (VGPR caps
// at 2 blocks/CU). Register ladder (measured): (256,2)->108-128 arch, no
// spill; (256,3)->84, partial spill, 2.3x slower; (256,4)->64, acc spill,
// 2.7x slower. NEVER raise the bound. Go/no-go: WRITE_SIZE ~8MB.
__global__ __launch_bounds__(256, 2) void attn_fwd(
    const unsigned short* __restrict__ Qb, const unsigned short* __restrict__ Kb,
    const unsigned short* __restrict__ Vt, const float* __restrict__ bias,
    unsigned short* __restrict__ Ob)
{
  __shared__ __attribute__((aligned(16))) unsigned char lds[65536];

  const int tid = (int)threadIdx.x;
  const int lane = tid & 63;
  const int w = tid >> 6;
  // XCD affinity: xcd = bid&7 owns heads [4*xcd, 4*xcd+4)
  const int bid = (int)blockIdx.x;
  const int bh = (bid & 7) * 4 + ((bid >> 3) & 3);
  const int qp = bid >> 5;                 // 0..31
  const int b = bh >> 4, h = bh & 15;
  const int tA = qp, tB = 63 - qp;
  const int q0A = tA * 32, q0B = tB * 32;
  const int ql = lane & 31;
  const int hi = lane >> 5;

  // ---- Q fragments (one-time gather) ----
  const unsigned short* QpA = Qb + (size_t)(b * 2048 + q0A + ql) * 1024 + h * 64 + 8 * hi;
  const unsigned short* QpB = Qb + (size_t)(b * 2048 + q0B + ql) * 1024 + h * 64 + 8 * hi;
  bf16x8 qfA[4], qfB[4];
#pragma unroll
  for (int c = 0; c < 4; ++c) {
    qfA[c] = *(const bf16x8*)(QpA + 16 * c);
    qfB[c] = *(const bf16x8*)(QpB + 16 * c);
  }

  // ---- per-lane staging sources (inverse-swizzled, rule #21) ----
  const unsigned short* KsrcL = Kb + (size_t)(b * 2048 + (lane >> 3)) * 1024
                                + h * 64 + (((lane & 7) ^ ((lane >> 3) & 7)) << 3);
  const unsigned short* VsrcL = Vt + (size_t)(bh * 64 + (lane >> 2)) * 2048
                                + (((lane & 3) ^ ((lane >> 2) & 3)) << 3);
  unsigned char* const Kdst = lds + w * 16384;  // per tile: K 4KB + V 4KB

  const float* BpA = bias + (size_t)b * 4194304 + (size_t)(q0A + ql) * 2048 + 4 * hi;
  const float* BpB = bias + (size_t)b * 4194304 + (size_t)(q0B + ql) * 2048 + 4 * hi;

  float plsA = 0.f, plsB = 0.f;
  f32x16 oA0 = {0.f,0.f,0.f,0.f,0.f,0.f,0.f,0.f,0.f,0.f,0.f,0.f,0.f,0.f,0.f,0.f};
  f32x16 oA1 = oA0, oB0 = oA0, oB1 = oA0;

  auto stageKV = [&](int kt, int off) {
    unsigned char* Kd = Kdst + off;
    unsigned char* Vd = Kd + 4096;
#pragma unroll
    for (int j = 0; j < 4; ++j)
      gl_lds16(KsrcL + (size_t)kt * 32768 + j * 8192, Kd + j * 1024);
#pragma unroll
    for (int j = 0; j < 4; ++j)
      gl_lds16(VsrcL + (size_t)j * 32768 + kt * 32, Vd + j * 1024);
  };
  auto ldfrags = [&](int off, bf16x8 (&kf)[4], bf16x8& va00, bf16x8& va01,
                     bf16x8& va10, bf16x8& va11) {
    const unsigned char* Ksh = Kdst + off;
    const unsigned char* Vsh = Ksh + 4096;
#pragma unroll
    for (int c = 0; c < 4; ++c)
      kf[c] = *(const bf16x8*)(Ksh + ql * 128 + (((hi + 2 * c) ^ (ql & 7)) << 4));
    const int vb = ((ql >> 4) << 10) + ((ql & 15) << 6);
    va00 = *(const bf16x8*)(Vsh + vb + (((hi) ^ (ql & 3)) << 4));
    va01 = *(const bf16x8*)(Vsh + vb + (((hi + 2) ^ (ql & 3)) << 4));
    va10 = *(const bf16x8*)(Vsh + 2048 + vb + (((hi) ^ (ql & 3)) << 4));
    va11 = *(const bf16x8*)(Vsh + 2048 + vb + (((hi + 2) ^ (ql & 3)) << 4));
  };

  for (int kt0 = 2 * w; kt0 <= tB; kt0 += 8) {
    const int kt1 = kt0 + 1;                 // kt0 even <= tB -> kt1 <= 63: stage-safe
    const bool doB1 = (kt1 <= tB);
    const bool doA0 = (kt0 <= tA);
    const bool doA1 = (kt1 <= tA);

    __builtin_amdgcn_sched_barrier(0);       // prev rounds' ds_reads stay above
    stageKV(kt0, 0);
    stageKV(kt1, 8192);
    f32x4 bB0[4], bB1[4], bA0[4], bA1[4];
#pragma unroll
    for (int j = 0; j < 4; ++j) bB0[j] = *(const f32x4*)(BpB + kt0 * 32 + 8 * j);
    if (doB1) {
#pragma unroll
      for (int j = 0; j < 4; ++j) bB1[j] = *(const f32x4*)(BpB + kt1 * 32 + 8 * j);
    }
    if (doA0) {
#pragma unroll
      for (int j = 0; j < 4; ++j) bA0[j] = *(const f32x4*)(BpA + kt0 * 32 + 8 * j);
    }
    if (doA1) {
#pragma unroll
      for (int j = 0; j < 4; ++j) bA1[j] = *(const f32x4*)(BpA + kt1 * 32 + 8 * j);
    }
    asm volatile("s_waitcnt vmcnt(0)" ::: "memory");  // stages + bias landed
    __builtin_amdgcn_sched_barrier(0);       // rule #18: fence before ds_reads

    {  // tile 0
      bf16x8 kf[4], va00, va01, va10, va11;
      ldfrags(0, kf, va00, va01, va10, va11);
      attn_chain(qfB, bB0, kf[0], kf[1], kf[2], kf[3], va00, va01, va10, va11,
                 kt0 == tB, ql, hi, oB0, oB1, plsB);
      if (doA0)
        attn_chain(qfA, bA0, kf[0], kf[1], kf[2], kf[3], va00, va01, va10, va11,
                   kt0 == tA, ql, hi, oA0, oA1, plsA);
    }
    if (doB1) {  // tile 1
      bf16x8 kf[4], va00, va01, va10, va11;
      ldfrags(8192, kf, va00, va01, va10, va11);
      attn_chain(qfB, bB1, kf[0], kf[1], kf[2], kf[3], va00, va01, va10, va11,
                 kt1 == tB, ql, hi, oB0, oB1, plsB);
      if (doA1)
        attn_chain(qfA, bA1, kf[0], kf[1], kf[2], kf[3], va00, va01, va10, va11,
                   kt1 == tA, ql, hi, oA0, oA1, plsA);
    }
  }

  // ---- cross-wave combine epilogue (aliased onto staging LDS) ----
  __syncthreads();                          // all waves done with staging LDS
  float* ldsF = (float*)lds;
  float* lsumbuf = ldsF + 8448;             // [2][256]
  float* rowinv = ldsF + 8960;              // [2][32]
  lsumbuf[(w * 2 + hi) * 32 + ql] = plsA;
  lsumbuf[256 + (w * 2 + hi) * 32 + ql] = plsB;
  if (w >= 2) {
    float* OA = ldsF + (w - 2) * 2112;          // Obuf[tile0][w-2]
    float* OB = ldsF + (2 + (w - 2)) * 2112;    // Obuf[tile1][w-2]
#pragma unroll
    for (int reg = 0; reg < 16; ++reg) {
      int d0 = (reg & 3) + 8 * (reg >> 2) + 4 * hi;
      OA[d0 * 33 + ql] = oA0[reg];
      OA[(d0 + 32) * 33 + ql] = oA1[reg];
      OB[d0 * 33 + ql] = oB0[reg];
      OB[(d0 + 32) * 33 + ql] = oB1[reg];
    }
  }
  __syncthreads();
  if (w < 2) {
    float* OA = ldsF + w * 2112;
    float* OB = ldsF + (2 + w) * 2112;
#pragma unroll
    for (int reg = 0; reg < 16; ++reg) {
      int d0 = (reg & 3) + 8 * (reg >> 2) + 4 * hi;
      OA[d0 * 33 + ql] += oA0[reg];
      OA[(d0 + 32) * 33 + ql] += oA1[reg];
      OB[d0 * 33 + ql] += oB0[reg];
      OB[(d0 + 32) * 33 + ql] += oB1[reg];
    }
  }
  __syncthreads();
  if (tid < 64) {
    int t = tid >> 5, q = tid & 31;
    float s = 0.f;
#pragma unroll
    for (int j = 0; j < 8; ++j) s += lsumbuf[t * 256 + j * 32 + q];
    rowinv[t * 32 + q] = frcp(s);
  }
  __syncthreads();
  // final write: d fastest -> 128B-contiguous global stores
#pragma unroll
  for (int it = 0; it < 16; ++it) {
    int i = it * 256 + tid;
    int t = i >> 11;
    int rem = i & 2047;
    int q = rem >> 6, d = rem & 63;
    float val = (ldsF[t * 4224 + d * 33 + q] + ldsF[t * 4224 + 2112 + d * 33 + q])
                * rowinv[t * 32 + q];
    int row = b * 2048 + (t ? q0B : q0A) + q;
    Ob[(size_t)row * 1024 + h * 64 + d] = f2b(val);
  }
}

extern "C" void kernel_launch(void* const* d_in, const int* in_sizes, int n_in,
                              void* d_out, int out_size, void* d_ws, size_t ws_size,
                              hipStream_t stream) {
  (void)in_sizes; (void)n_in; (void)out_size; (void)ws_size;
  const float* inp  = (const float*)d_in[0];
  const float* bias = (const float*)d_in[1];
  // d_in[2] = attn_mask (causal, recomputed in-kernel)
  const float* wq = (const float*)d_in[3];
  const float* wk = (const float*)d_in[4];
  const float* wv = (const float*)d_in[5];
  const float* wo = (const float*)d_in[6];
  float* out = (float*)d_out;

  unsigned short* Xb   = (unsigned short*)d_ws;     // 4096x1024 bf16
  unsigned short* Wcat = Xb + 4194304;              // 4 x 1024x1024 bf16
  unsigned short* Qb   = Wcat + 4194304;            // 4096x1024
  unsigned short* Kb   = Qb + 4194304;              // 4096x1024
  unsigned short* Vt   = Kb + 4194304;              // (2*16*64) x 2048
  unsigned short* Ob   = Vt + 4194304;              // 4096x1024

  convert_kernel<<<8192, 256, 0, stream>>>(inp, wq, wk, wv, wo, Xb, Wcat);
  gemm_qkv<<<dim3(32, 8, 3), dim3(256), 0, stream>>>(Xb, Wcat, Qb, Kb, Vt);
  attn_fwd<<<1024, 256, 0, stream>>>(Qb, Kb, Vt, bias, Ob);
  gemm_out<<<dim3(32, 8, 1), dim3(256), 0, stream>>>(Ob, Wcat + 3 * 1048576, out);
}